// Round 4
// baseline (1286.604 us; speedup 1.0000x reference)
//
#include <hip/hip_runtime.h>

// Problem constants (B, L, H, D) = (4, 4096, 8, 64), FACTOR=5
// Inputs/outputs are float32 per the reference (jnp.float32).
#define NB 4
#define LSEQ 4096
#define NH 8
#define ND 64
#define NSAMP 45
#define NTOP 45

// ---------------------------------------------------------------------------
// Kernel 1: M[b,h,l] = max_s(q.k_s) - sum_s(q.k_s)/LSEQ over 45 sampled keys.
// One wave per (b,l,h); lane = d. UNCHANGED from round 3 — its exact fp
// ordering determines the top-k selection set (absmax 1.0 is a boundary
// artifact; do not perturb).
// ---------------------------------------------------------------------------
__global__ __launch_bounds__(256) void compute_M_kernel(
        const float* __restrict__ Q,
        const float* __restrict__ K,
        const int* __restrict__ idxS,
        float* __restrict__ Mout) {
    int w = blockIdx.x * 4 + (threadIdx.x >> 6);   // w = ((b*LSEQ + l)*NH + h)
    int lane = threadIdx.x & 63;
    int h = w & (NH - 1);
    int bl = w >> 3;
    int l = bl & (LSEQ - 1);
    int b = bl >> 12;

    float q = Q[(size_t)w * ND + lane];
    const int* is = idxS + (size_t)l * NSAMP;

    float maxv = -INFINITY;
    float sumv = 0.0f;
    for (int s = 0; s < NSAMP; ++s) {
        int idx = is[s];
        float k = K[(((size_t)b * LSEQ + idx) * NH + h) * ND + lane];
        float p = q * k;
        #pragma unroll
        for (int off = 32; off; off >>= 1) p += __shfl_xor(p, off, 64);
        maxv = fmaxf(maxv, p);
        sumv += p;
    }
    if (lane == 0)
        Mout[((size_t)b * NH + h) * LSEQ + l] = maxv - sumv * (1.0f / (float)LSEQ);
}

// ---------------------------------------------------------------------------
// Kernel 2: top-45 per (b,h). One block (256 thr) per (b,h).
// Candidates live in REGISTERS (16/thread); wave shuffle argmax + tiny LDS
// cross-wave combine. Tie-break: lowest index (identical to round 3 / lax).
// ---------------------------------------------------------------------------
__global__ __launch_bounds__(256) void topk_kernel(
        const float* __restrict__ M, int* __restrict__ Mtop) {
    int bh = blockIdx.x;
    int t = threadIdx.x;
    int wave = t >> 6, lane = t & 63;
    const float* m = M + (size_t)bh * LSEQ;

    float rv[16];
    #pragma unroll
    for (int k = 0; k < 16; ++k) rv[k] = m[t + (k << 8)];

    __shared__ float wv[4];
    __shared__ int   wi[4];
    __shared__ int   winIdx;

    for (int iter = 0; iter < NTOP; ++iter) {
        float bv = -INFINITY; int bi = 0x7fffffff;
        #pragma unroll
        for (int k = 0; k < 16; ++k) {           // ascending idx, strict > => lowest idx on ties
            float v = rv[k];
            if (v > bv) { bv = v; bi = t + (k << 8); }
        }
        #pragma unroll
        for (int off = 1; off < 64; off <<= 1) {
            float ov = __shfl_xor(bv, off, 64);
            int   oi = __shfl_xor(bi, off, 64);
            if (ov > bv || (ov == bv && oi < bi)) { bv = ov; bi = oi; }
        }
        if (lane == 0) { wv[wave] = bv; wi[wave] = bi; }
        __syncthreads();
        if (t == 0) {
            float cv = wv[0]; int ci = wi[0];
            for (int ww = 1; ww < 4; ++ww) {
                if (wv[ww] > cv || (wv[ww] == cv && wi[ww] < ci)) { cv = wv[ww]; ci = wi[ww]; }
            }
            winIdx = ci;
            Mtop[bh * NTOP + iter] = ci;
        }
        __syncthreads();
        int widx = winIdx;
        #pragma unroll
        for (int k = 0; k < 16; ++k)
            if (widx == t + (k << 8)) rv[k] = -INFINITY;
        __syncthreads();
    }
}

// ---------------------------------------------------------------------------
// Kernel 3: cumsum of V along L -> out (B,H,L,D) fp32.
// One block (256 thr) per (b,h,chunk) — 512 blocks. Prefix over earlier rows
// recomputed redundantly (L2-hot), no global scratch, no multi-kernel scan.
// ---------------------------------------------------------------------------
__global__ __launch_bounds__(256) void cumsum_kernel(
        const float* __restrict__ V, float* __restrict__ out) {
    const int NCH = 16, CH = LSEQ / NCH;   // 16 chunks x 256 rows
    int blk = blockIdx.x;
    int c = blk & (NCH - 1);
    int bh = blk >> 4;
    int h = bh & (NH - 1);
    int b = bh >> 3;
    int t = threadIdx.x;
    int g = t >> 6, d = t & 63;

    const size_t rstride = (size_t)NH * ND;   // 512
    size_t vbase = (size_t)b * LSEQ * rstride + (size_t)h * ND + d;

    int pre = c * CH;                 // rows before this chunk
    // quarter of prefix range
    float ps = 0.0f;
    int q0 = g * (pre >> 2), q1 = (g + 1) * (pre >> 2);
    for (int l = q0; l < q1; ++l) ps += V[vbase + (size_t)l * rstride];
    // own 64-row sub-chunk sum
    float ss = 0.0f;
    int s0 = pre + g * 64;
    for (int l = s0; l < s0 + 64; ++l) ss += V[vbase + (size_t)l * rstride];

    __shared__ float pq[4][ND], sq[4][ND];
    pq[g][d] = ps; sq[g][d] = ss;
    __syncthreads();

    float run = pq[0][d] + pq[1][d] + pq[2][d] + pq[3][d];
    for (int gg = 0; gg < g; ++gg) run += sq[gg][d];

    size_t obase = (size_t)bh * LSEQ * ND + d;
    for (int l = s0; l < s0 + 64; ++l) {
        run += V[vbase + (size_t)l * rstride];
        out[obase + (size_t)l * ND] = run;
    }
}

// ---------------------------------------------------------------------------
// Kernel 4: flash-style single pass. One block (512 thr = 8 waves) per
// (b,h,u). Each wave: lane=d, rows j = wave, wave+8, ... Coalesced 256 B
// K/V row loads, butterfly dot, online softmax (m,s,o) in registers.
// ---------------------------------------------------------------------------
__global__ __launch_bounds__(512) void attn_rows_kernel(
        const float* __restrict__ Q,
        const float* __restrict__ K,
        const float* __restrict__ V,
        const int* __restrict__ Mtop,
        float* __restrict__ out) {
    int u  = blockIdx.x % NTOP;
    int bh = blockIdx.x / NTOP;
    int h = bh & (NH - 1);
    int b = bh >> 3;
    int pos = Mtop[bh * NTOP + u];
    int n = pos + 1;
    int tid = threadIdx.x;
    int wave = tid >> 6, lane = tid & 63;   // lane == d

    const size_t rstride = (size_t)NH * ND;   // 512
    size_t rowbase = (size_t)b * LSEQ * rstride + (size_t)h * ND + lane;

    float qd = Q[rowbase + (size_t)pos * rstride];

    float m = -INFINITY, s = 0.0f, o = 0.0f;

    for (int j = wave; j < n; j += 8) {
        size_t r = rowbase + (size_t)j * rstride;
        float kd = K[r];
        float vd = V[r];
        float p = qd * kd;
        #pragma unroll
        for (int off = 32; off; off >>= 1) p += __shfl_xor(p, off, 64);
        float sc = p * 0.125f;                 // 1/sqrt(64); uniform across wave
        if (sc > m) {                          // wave-uniform branch (rare)
            float alpha = __expf(m - sc);      // m=-inf first time -> alpha=0
            s = s * alpha + 1.0f;
            o = o * alpha + vd;
            m = sc;
        } else {
            float pj = __expf(sc - m);
            s += pj;
            o += pj * vd;
        }
    }

    __shared__ float cm[8], cs[8], co[8][ND];
    if (lane == 0) { cm[wave] = m; cs[wave] = s; }
    co[wave][lane] = o;
    __syncthreads();

    if (wave == 0) {
        float mstar = cm[0];
        #pragma unroll
        for (int w = 1; w < 8; ++w) mstar = fmaxf(mstar, cm[w]);
        float stot = 0.0f, otot = 0.0f;
        #pragma unroll
        for (int w = 0; w < 8; ++w) {
            float a = __expf(cm[w] - mstar);   // cm=-inf (idle wave) -> 0
            stot += cs[w] * a;
            otot += co[w][lane] * a;
        }
        out[((size_t)bh * LSEQ + pos) * ND + lane] = otot / stot;
    }
}

// ---------------------------------------------------------------------------
extern "C" void kernel_launch(void* const* d_in, const int* in_sizes, int n_in,
                              void* d_out, int out_size, void* d_ws, size_t ws_size,
                              hipStream_t stream) {
    const float* Q = (const float*)d_in[0];
    const float* K = (const float*)d_in[1];
    const float* V = (const float*)d_in[2];
    const int* idxS = (const int*)d_in[3];
    float* out = (float*)d_out;

    // M (fp32, 512 KB) lives in d_out — consumed by topk before cumsum
    // overwrites d_out. Only Mtop (5760 B) uses the workspace.
    float* Mbuf = (float*)d_out;
    int*   Mtop = (int*)d_ws;

    compute_M_kernel<<<NB * LSEQ * NH / 4, 256, 0, stream>>>(Q, K, idxS, Mbuf);
    topk_kernel<<<NB * NH, 256, 0, stream>>>(Mbuf, Mtop);
    cumsum_kernel<<<NB * NH * 16, 256, 0, stream>>>(V, out);
    attn_rows_kernel<<<NB * NH * NTOP, 512, 0, stream>>>(Q, K, V, Mtop, out);
}

// Round 5
// 995.818 us; speedup vs baseline: 1.2920x; 1.2920x over previous
//
#include <hip/hip_runtime.h>

// Problem constants (B, L, H, D) = (4, 4096, 8, 64), FACTOR=5
// Inputs/outputs are float32 per the reference (jnp.float32).
#define NB 4
#define LSEQ 4096
#define NH 8
#define ND 64
#define NSAMP 45
#define NTOP 45

// ---------------------------------------------------------------------------
// Kernel 1: M[b,h,l] = max_s(q.k_s) - sum_s(q.k_s)/LSEQ over 45 sampled keys.
// One wave per (b,l,h); lane = d. BATCHED 8 samples/iter: 8 independent
// load+butterfly chains interleaved by the compiler -> ~8x fewer chain
// stalls. fmax/sum application order is IDENTICAL to the round-3/4 version
// (bit-identical M => identical top-k selection).
// ---------------------------------------------------------------------------
__global__ __launch_bounds__(256) void compute_M_kernel(
        const float* __restrict__ Q,
        const float* __restrict__ K,
        const int* __restrict__ idxS,
        float* __restrict__ Mout) {
    int w = blockIdx.x * 4 + (threadIdx.x >> 6);   // w = ((b*LSEQ + l)*NH + h)
    int lane = threadIdx.x & 63;
    int h = w & (NH - 1);
    int bl = w >> 3;
    int l = bl & (LSEQ - 1);
    int b = bl >> 12;

    float q = Q[(size_t)w * ND + lane];
    const int* is = idxS + (size_t)l * NSAMP;
    size_t kbase = ((size_t)b * LSEQ * NH + h) * ND + lane;

    float maxv = -INFINITY;
    float sumv = 0.0f;

    #pragma unroll
    for (int s0 = 0; s0 < NSAMP; s0 += 8) {
        float p[8];
        #pragma unroll
        for (int i = 0; i < 8; ++i) {
            int s = s0 + i;
            int idx = is[(s < NSAMP) ? s : (NSAMP - 1)];
            float k = K[kbase + (size_t)idx * (NH * ND)];
            p[i] = q * k;
        }
        // 8 independent butterflies (same pattern per sample as before)
        #pragma unroll
        for (int off = 32; off; off >>= 1) {
            #pragma unroll
            for (int i = 0; i < 8; ++i) p[i] += __shfl_xor(p[i], off, 64);
        }
        // apply in ascending s order -> bit-identical to serial version
        #pragma unroll
        for (int i = 0; i < 8; ++i) {
            if (s0 + i < NSAMP) {          // compile-time per unrolled i
                maxv = fmaxf(maxv, p[i]);
                sumv += p[i];
            }
        }
    }
    if (lane == 0)
        Mout[((size_t)b * NH + h) * LSEQ + l] = maxv - sumv * (1.0f / (float)LSEQ);
}

// ---------------------------------------------------------------------------
// Kernel 2: top-45 per (b,h). One block (256 thr) per (b,h).
// Register-resident candidates + shuffle argmax. Lowest-index tie-break.
// ---------------------------------------------------------------------------
__global__ __launch_bounds__(256) void topk_kernel(
        const float* __restrict__ M, int* __restrict__ Mtop) {
    int bh = blockIdx.x;
    int t = threadIdx.x;
    int wave = t >> 6, lane = t & 63;
    const float* m = M + (size_t)bh * LSEQ;

    float rv[16];
    #pragma unroll
    for (int k = 0; k < 16; ++k) rv[k] = m[t + (k << 8)];

    __shared__ float wv[4];
    __shared__ int   wi[4];
    __shared__ int   winIdx;

    for (int iter = 0; iter < NTOP; ++iter) {
        float bv = -INFINITY; int bi = 0x7fffffff;
        #pragma unroll
        for (int k = 0; k < 16; ++k) {
            float v = rv[k];
            if (v > bv) { bv = v; bi = t + (k << 8); }
        }
        #pragma unroll
        for (int off = 1; off < 64; off <<= 1) {
            float ov = __shfl_xor(bv, off, 64);
            int   oi = __shfl_xor(bi, off, 64);
            if (ov > bv || (ov == bv && oi < bi)) { bv = ov; bi = oi; }
        }
        if (lane == 0) { wv[wave] = bv; wi[wave] = bi; }
        __syncthreads();
        if (t == 0) {
            float cv = wv[0]; int ci = wi[0];
            for (int ww = 1; ww < 4; ++ww) {
                if (wv[ww] > cv || (wv[ww] == cv && wi[ww] < ci)) { cv = wv[ww]; ci = wi[ww]; }
            }
            winIdx = ci;
            Mtop[bh * NTOP + iter] = ci;
        }
        __syncthreads();
        int widx = winIdx;
        #pragma unroll
        for (int k = 0; k < 16; ++k)
            if (widx == t + (k << 8)) rv[k] = -INFINITY;
        __syncthreads();
    }
}

// ---------------------------------------------------------------------------
// Kernel 3: cumsum of V along L -> out (B,H,L,D) fp32.
// One block (512 thr = 8 groups) per (b,h,chunk of 256 rows) — 512 blocks.
// Prefix recomputed redundantly (8-way split, <=480 serial iters/thread).
// ---------------------------------------------------------------------------
__global__ __launch_bounds__(512) void cumsum_kernel(
        const float* __restrict__ V, float* __restrict__ out) {
    const int NCH = 16, CH = LSEQ / NCH;   // 16 chunks x 256 rows
    int blk = blockIdx.x;
    int c = blk & (NCH - 1);
    int bh = blk >> 4;
    int h = bh & (NH - 1);
    int b = bh >> 3;
    int t = threadIdx.x;
    int g = t >> 6, d = t & 63;            // 8 groups of one wave

    const size_t rstride = (size_t)NH * ND;   // 512
    size_t vbase = (size_t)b * LSEQ * rstride + (size_t)h * ND + d;

    int pre = c * CH;                      // rows before this chunk (mult of 8)
    float ps = 0.0f;
    int q0 = g * (pre >> 3), q1 = (g + 1) * (pre >> 3);
    for (int l = q0; l < q1; ++l) ps += V[vbase + (size_t)l * rstride];

    float ss = 0.0f;
    int s0 = pre + g * 32;                 // own 32-row sub-chunk
    for (int l = s0; l < s0 + 32; ++l) ss += V[vbase + (size_t)l * rstride];

    __shared__ float pq[8][ND], sq[8][ND];
    pq[g][d] = ps; sq[g][d] = ss;
    __syncthreads();

    float run = 0.0f;
    #pragma unroll
    for (int gg = 0; gg < 8; ++gg) run += pq[gg][d];
    for (int gg = 0; gg < g; ++gg) run += sq[gg][d];

    size_t obase = (size_t)bh * LSEQ * ND + d;
    for (int l = s0; l < s0 + 32; ++l) {
        run += V[vbase + (size_t)l * rstride];
        out[obase + (size_t)l * ND] = run;
    }
}

// ---------------------------------------------------------------------------
// Kernel 4: flash-style single pass, BATCHED 8 rows/iter. One block
// (512 thr = 8 waves) per (b,h,u). Wave w handles j in {w*8+k*64+i}.
// 8 independent load+butterfly chains per iteration; one m/s/o update.
// ---------------------------------------------------------------------------
__global__ __launch_bounds__(512) void attn_rows_kernel(
        const float* __restrict__ Q,
        const float* __restrict__ K,
        const float* __restrict__ V,
        const int* __restrict__ Mtop,
        float* __restrict__ out) {
    int u  = blockIdx.x % NTOP;
    int bh = blockIdx.x / NTOP;
    int h = bh & (NH - 1);
    int b = bh >> 3;
    int pos = Mtop[bh * NTOP + u];
    int n = pos + 1;
    int tid = threadIdx.x;
    int wave = tid >> 6, lane = tid & 63;   // lane == d

    const size_t rstride = (size_t)NH * ND;   // 512
    size_t rowbase = (size_t)b * LSEQ * rstride + (size_t)h * ND + lane;

    float qd = Q[rowbase + (size_t)pos * rstride];

    float m = -INFINITY, s = 0.0f, o = 0.0f;

    for (int j0 = wave * 8; j0 < n; j0 += 64) {
        float p[8], vd[8];
        #pragma unroll
        for (int i = 0; i < 8; ++i) {
            int j = j0 + i;
            int jc = (j < n) ? j : pos;          // clamp (masked later)
            size_t r = rowbase + (size_t)jc * rstride;
            float kd = K[r];
            vd[i] = V[r];
            p[i] = qd * kd;
        }
        #pragma unroll
        for (int off = 32; off; off >>= 1) {
            #pragma unroll
            for (int i = 0; i < 8; ++i) p[i] += __shfl_xor(p[i], off, 64);
        }
        float sc[8];
        #pragma unroll
        for (int i = 0; i < 8; ++i)
            sc[i] = (j0 + i < n) ? p[i] * 0.125f : -INFINITY;

        // batch max (tree)
        float bm01 = fmaxf(sc[0], sc[1]), bm23 = fmaxf(sc[2], sc[3]);
        float bm45 = fmaxf(sc[4], sc[5]), bm67 = fmaxf(sc[6], sc[7]);
        float bm = fmaxf(fmaxf(bm01, bm23), fmaxf(bm45, bm67));

        if (bm > m) {                            // wave-uniform
            float alpha = __expf(m - bm);        // m=-inf first time -> 0
            s *= alpha; o *= alpha; m = bm;
        }
        float e[8];
        #pragma unroll
        for (int i = 0; i < 8; ++i) e[i] = __expf(sc[i] - m);  // masked -> 0
        #pragma unroll
        for (int i = 0; i < 8; ++i) { s += e[i]; o += e[i] * vd[i]; }
    }

    __shared__ float cm[8], cs[8], co[8][ND];
    if (lane == 0) { cm[wave] = m; cs[wave] = s; }
    co[wave][lane] = o;
    __syncthreads();

    if (wave == 0) {
        float mstar = cm[0];
        #pragma unroll
        for (int w = 1; w < 8; ++w) mstar = fmaxf(mstar, cm[w]);
        float stot = 0.0f, otot = 0.0f;
        #pragma unroll
        for (int w = 0; w < 8; ++w) {
            float a = __expf(cm[w] - mstar);     // empty wave: exp(-inf)=0
            stot += cs[w] * a;
            otot += co[w][lane] * a;
        }
        out[((size_t)bh * LSEQ + pos) * ND + lane] = otot / stot;
    }
}

// ---------------------------------------------------------------------------
extern "C" void kernel_launch(void* const* d_in, const int* in_sizes, int n_in,
                              void* d_out, int out_size, void* d_ws, size_t ws_size,
                              hipStream_t stream) {
    const float* Q = (const float*)d_in[0];
    const float* K = (const float*)d_in[1];
    const float* V = (const float*)d_in[2];
    const int* idxS = (const int*)d_in[3];
    float* out = (float*)d_out;

    // M (fp32, 512 KB) lives in d_out — consumed by topk before cumsum
    // overwrites d_out. Only Mtop (5760 B) uses the workspace.
    float* Mbuf = (float*)d_out;
    int*   Mtop = (int*)d_ws;

    compute_M_kernel<<<NB * LSEQ * NH / 4, 256, 0, stream>>>(Q, K, idxS, Mbuf);
    topk_kernel<<<NB * NH, 256, 0, stream>>>(Mbuf, Mtop);
    cumsum_kernel<<<NB * NH * 16, 512, 0, stream>>>(V, out);
    attn_rows_kernel<<<NB * NH * NTOP, 512, 0, stream>>>(Q, K, V, Mtop, out);
}

// Round 6
// 795.602 us; speedup vs baseline: 1.6171x; 1.2517x over previous
//
#include <hip/hip_runtime.h>

// Problem constants (B, L, H, D) = (4, 4096, 8, 64), FACTOR=5
// Inputs/outputs are float32 per the reference (jnp.float32).
#define NB 4
#define LSEQ 4096
#define NH 8
#define ND 64
#define NSAMP 45
#define NTOP 45

// ---------------------------------------------------------------------------
// Kernel 1: M[b,h,l] = max_s(q.k_s) - sum_s(q.k_s)/LSEQ over 45 sampled keys.
// ONE THREAD per (b,h,l): full 64-elem dot per sample, summed with the EXACT
// binary tree the old 64-lane butterfly used (p[i]+=p[i+off], off=32..1 ==
// lane-0 cone of shfl_xor butterfly; fp add commutative => identical bits).
// __fmul_rn/__fadd_rn forbid FMA contraction. fmax/sum order ascending in s,
// final expression verbatim => bit-identical M => identical top-k selection.
// ---------------------------------------------------------------------------
__global__ __launch_bounds__(256) void compute_M_kernel(
        const float* __restrict__ Q,
        const float* __restrict__ K,
        const int* __restrict__ idxS,
        float* __restrict__ Mout) {
    int t = blockIdx.x * 256 + threadIdx.x;   // t = ((b*NH+h)*LSEQ + l)
    int l = t & (LSEQ - 1);
    int bh = t >> 12;
    int h = bh & (NH - 1);
    int b = bh >> 3;

    const float4* qp = reinterpret_cast<const float4*>(
        Q + (((size_t)b * LSEQ + l) * NH + h) * ND);
    float4 q4[16];
    #pragma unroll
    for (int i = 0; i < 16; ++i) q4[i] = qp[i];

    const int* is = idxS + (size_t)l * NSAMP;
    size_t kbh = ((size_t)b * LSEQ * NH + h) * ND;

    float maxv = -INFINITY;
    float sumv = 0.0f;

    for (int s = 0; s < NSAMP; ++s) {
        int idx = is[s];
        const float4* kp = reinterpret_cast<const float4*>(
            K + kbh + (size_t)idx * (NH * ND));
        float4 k4[16];
        #pragma unroll
        for (int i = 0; i < 16; ++i) k4[i] = kp[i];

        // stage off=32 fused with products: w[j] = p[j] + p[j+32]
        float w[32];
        #pragma unroll
        for (int i = 0; i < 8; ++i) {
            float4 a = q4[i], bb = k4[i], c = q4[i + 8], d4 = k4[i + 8];
            w[4 * i + 0] = __fadd_rn(__fmul_rn(a.x, bb.x), __fmul_rn(c.x, d4.x));
            w[4 * i + 1] = __fadd_rn(__fmul_rn(a.y, bb.y), __fmul_rn(c.y, d4.y));
            w[4 * i + 2] = __fadd_rn(__fmul_rn(a.z, bb.z), __fmul_rn(c.z, d4.z));
            w[4 * i + 3] = __fadd_rn(__fmul_rn(a.w, bb.w), __fmul_rn(c.w, d4.w));
        }
        // stages off=16,8,4,2,1
        #pragma unroll
        for (int off = 16; off; off >>= 1) {
            #pragma unroll
            for (int i = 0; i < off; ++i) w[i] = __fadd_rn(w[i], w[i + off]);
        }
        float p = w[0];
        maxv = fmaxf(maxv, p);
        sumv = __fadd_rn(sumv, p);
    }
    Mout[t] = maxv - sumv * (1.0f / (float)LSEQ);
}

// ---------------------------------------------------------------------------
// Kernel 2: top-45 per (b,h). UNCHANGED (selection semantics frozen).
// ---------------------------------------------------------------------------
__global__ __launch_bounds__(256) void topk_kernel(
        const float* __restrict__ M, int* __restrict__ Mtop) {
    int bh = blockIdx.x;
    int t = threadIdx.x;
    int wave = t >> 6, lane = t & 63;
    const float* m = M + (size_t)bh * LSEQ;

    float rv[16];
    #pragma unroll
    for (int k = 0; k < 16; ++k) rv[k] = m[t + (k << 8)];

    __shared__ float wv[4];
    __shared__ int   wi[4];
    __shared__ int   winIdx;

    for (int iter = 0; iter < NTOP; ++iter) {
        float bv = -INFINITY; int bi = 0x7fffffff;
        #pragma unroll
        for (int k = 0; k < 16; ++k) {
            float v = rv[k];
            if (v > bv) { bv = v; bi = t + (k << 8); }
        }
        #pragma unroll
        for (int off = 1; off < 64; off <<= 1) {
            float ov = __shfl_xor(bv, off, 64);
            int   oi = __shfl_xor(bi, off, 64);
            if (ov > bv || (ov == bv && oi < bi)) { bv = ov; bi = oi; }
        }
        if (lane == 0) { wv[wave] = bv; wi[wave] = bi; }
        __syncthreads();
        if (t == 0) {
            float cv = wv[0]; int ci = wi[0];
            for (int ww = 1; ww < 4; ++ww) {
                if (wv[ww] > cv || (wv[ww] == cv && wi[ww] < ci)) { cv = wv[ww]; ci = wi[ww]; }
            }
            winIdx = ci;
            Mtop[bh * NTOP + iter] = ci;
        }
        __syncthreads();
        int widx = winIdx;
        #pragma unroll
        for (int k = 0; k < 16; ++k)
            if (widx == t + (k << 8)) rv[k] = -INFINITY;
        __syncthreads();
    }
}

// ---------------------------------------------------------------------------
// Kernel 3: cumsum of V along L -> out (B,H,L,D) fp32. UNCHANGED.
// ---------------------------------------------------------------------------
__global__ __launch_bounds__(512) void cumsum_kernel(
        const float* __restrict__ V, float* __restrict__ out) {
    const int NCH = 16, CH = LSEQ / NCH;
    int blk = blockIdx.x;
    int c = blk & (NCH - 1);
    int bh = blk >> 4;
    int h = bh & (NH - 1);
    int b = bh >> 3;
    int t = threadIdx.x;
    int g = t >> 6, d = t & 63;

    const size_t rstride = (size_t)NH * ND;
    size_t vbase = (size_t)b * LSEQ * rstride + (size_t)h * ND + d;

    int pre = c * CH;
    float ps = 0.0f;
    int q0 = g * (pre >> 3), q1 = (g + 1) * (pre >> 3);
    for (int l = q0; l < q1; ++l) ps += V[vbase + (size_t)l * rstride];

    float ss = 0.0f;
    int s0 = pre + g * 32;
    for (int l = s0; l < s0 + 32; ++l) ss += V[vbase + (size_t)l * rstride];

    __shared__ float pq[8][ND], sq[8][ND];
    pq[g][d] = ps; sq[g][d] = ss;
    __syncthreads();

    float run = 0.0f;
    #pragma unroll
    for (int gg = 0; gg < 8; ++gg) run += pq[gg][d];
    for (int gg = 0; gg < g; ++gg) run += sq[gg][d];

    size_t obase = (size_t)bh * LSEQ * ND + d;
    for (int l = s0; l < s0 + 32; ++l) {
        run += V[vbase + (size_t)l * rstride];
        out[obase + (size_t)l * ND] = run;
    }
}

// ---------------------------------------------------------------------------
// Kernel 4: per (b,h,u) flash attention, LDS-tiled. 256 thr = (row r = t>>2,
// quarter qt = t&3). 64-row K/V tiles staged coalesced into padded LDS
// (stride 65 => 2-way banks = free). Quarter-dot (16 FMA) + 2 shuffles.
// Online softmax per thread; block combine at end. Only 2 shuffles/row.
// ---------------------------------------------------------------------------
#define TJ 64
__global__ __launch_bounds__(256) void attn_rows_kernel(
        const float* __restrict__ Q,
        const float* __restrict__ K,
        const float* __restrict__ V,
        const int* __restrict__ Mtop,
        float* __restrict__ out) {
    int u  = blockIdx.x % NTOP;
    int bh = blockIdx.x / NTOP;
    int h = bh & (NH - 1);
    int b = bh >> 3;
    int pos = Mtop[bh * NTOP + u];
    int n = pos + 1;
    int t = threadIdx.x;
    int r = t >> 2, qt = t & 3;

    __shared__ float Ks[TJ][65];
    __shared__ float Vs[TJ][65];
    __shared__ float red[256];

    const size_t rstride = (size_t)NH * ND;   // 512
    size_t base = (size_t)b * LSEQ * rstride + (size_t)h * ND;

    // q quarter into registers
    float qreg[16];
    const float* qrow = Q + base + (size_t)pos * rstride + qt * 16;
    #pragma unroll
    for (int i = 0; i < 16; i += 4) {
        float4 v4 = *reinterpret_cast<const float4*>(qrow + i);
        qreg[i] = v4.x; qreg[i + 1] = v4.y; qreg[i + 2] = v4.z; qreg[i + 3] = v4.w;
    }

    float m = -INFINITY, s = 0.0f;
    float o[16];
    #pragma unroll
    for (int dd = 0; dd < 16; ++dd) o[dd] = 0.0f;

    int ntiles = (n + TJ - 1) / TJ;
    for (int tt = 0; tt < ntiles; ++tt) {
        int j0 = tt * TJ;
        __syncthreads();   // protect previous tile's LDS reads
        // stage K,V tile: 1024 float4 each; thread does 4 of each, coalesced
        #pragma unroll
        for (int i = 0; i < 4; ++i) {
            int u16 = t + i * 256;
            int rr = u16 >> 4, cc = u16 & 15;
            int j = j0 + rr;
            int jc = (j < n) ? j : (n - 1);
            const float* rowk = K + base + (size_t)jc * rstride;
            float4 kv = *reinterpret_cast<const float4*>(rowk + cc * 4);
            Ks[rr][cc * 4 + 0] = kv.x; Ks[rr][cc * 4 + 1] = kv.y;
            Ks[rr][cc * 4 + 2] = kv.z; Ks[rr][cc * 4 + 3] = kv.w;
            const float* rowv = V + base + (size_t)jc * rstride;
            float4 vv = *reinterpret_cast<const float4*>(rowv + cc * 4);
            Vs[rr][cc * 4 + 0] = vv.x; Vs[rr][cc * 4 + 1] = vv.y;
            Vs[rr][cc * 4 + 2] = vv.z; Vs[rr][cc * 4 + 3] = vv.w;
        }
        __syncthreads();

        int j = j0 + r;
        float acc = 0.0f;
        #pragma unroll
        for (int dd = 0; dd < 16; ++dd)
            acc = fmaf(qreg[dd], Ks[r][qt * 16 + dd], acc);
        acc += __shfl_xor(acc, 1, 64);
        acc += __shfl_xor(acc, 2, 64);

        if (j < n) {
            float sc = acc * 0.125f;   // 1/sqrt(64)
            if (sc > m) {
                float alpha = __expf(m - sc);   // m=-inf first time -> 0
                s *= alpha;
                #pragma unroll
                for (int dd = 0; dd < 16; ++dd) o[dd] *= alpha;
                m = sc;
            }
            float e = __expf(sc - m);
            s += e;
            #pragma unroll
            for (int dd = 0; dd < 16; ++dd)
                o[dd] = fmaf(e, Vs[r][qt * 16 + dd], o[dd]);
        }
    }
    __syncthreads();

    // block combine: max m
    red[t] = m; __syncthreads();
    for (int sft = 128; sft; sft >>= 1) {
        if (t < sft) red[t] = fmaxf(red[t], red[t + sft]);
        __syncthreads();
    }
    float mstar = red[0]; __syncthreads();
    float a = __expf(m - mstar);      // m=-inf (no rows) -> 0

    red[t] = s * a; __syncthreads();
    for (int sft = 128; sft; sft >>= 1) {
        if (t < sft) red[t] += red[t + sft];
        __syncthreads();
    }
    float S = red[0]; __syncthreads();

    // o combine via reused Ks LDS: OB[t*16+dd]
    float* OB = &Ks[0][0];            // 64*65 = 4160 floats >= 4096
    #pragma unroll
    for (int dd = 0; dd < 16; ++dd) OB[t * 16 + dd] = o[dd] * a;
    __syncthreads();

    if (t < ND) {
        int qtt = t >> 4, dd = t & 15;
        float tot = 0.0f;
        for (int k = 0; k < 64; ++k) tot += OB[(4 * k + qtt) * 16 + dd];
        out[((size_t)bh * LSEQ + pos) * ND + t] = tot / S;
    }
}

// ---------------------------------------------------------------------------
extern "C" void kernel_launch(void* const* d_in, const int* in_sizes, int n_in,
                              void* d_out, int out_size, void* d_ws, size_t ws_size,
                              hipStream_t stream) {
    const float* Q = (const float*)d_in[0];
    const float* K = (const float*)d_in[1];
    const float* V = (const float*)d_in[2];
    const int* idxS = (const int*)d_in[3];
    float* out = (float*)d_out;

    // M (fp32, 512 KB) lives in d_out — consumed by topk before cumsum
    // overwrites d_out. Only Mtop (5760 B) uses the workspace.
    float* Mbuf = (float*)d_out;
    int*   Mtop = (int*)d_ws;

    compute_M_kernel<<<NB * NH * LSEQ / 256, 256, 0, stream>>>(Q, K, idxS, Mbuf);
    topk_kernel<<<NB * NH, 256, 0, stream>>>(Mbuf, Mtop);
    cumsum_kernel<<<NB * NH * 16, 512, 0, stream>>>(V, out);
    attn_rows_kernel<<<NB * NH * NTOP, 256, 0, stream>>>(Q, K, V, Mtop, out);
}

// Round 7
// 619.221 us; speedup vs baseline: 2.0778x; 1.2848x over previous
//
#include <hip/hip_runtime.h>

// Problem constants (B, L, H, D) = (4, 4096, 8, 64), FACTOR=5
// Inputs/outputs are float32 per the reference (jnp.float32).
#define NB 4
#define LSEQ 4096
#define NH 8
#define ND 64
#define NSAMP 45
#define NTOP 45

// ---------------------------------------------------------------------------
// Kernel 1: M[b,h,l] = max_s(q.k_s) - sum_s(q.k_s)/LSEQ over 45 sampled keys.
// ONE THREAD per (b,h,l) with the EXACT butterfly-equivalent add tree
// (bit-identical M across rounds => selection frozen). Thread remap vs r6:
// h is in the LOW lane bits, so 8 adjacent lanes share l (same idx) and
// their K rows form one contiguous 2 KB chunk -> L1-line reuse kills the
// scattered-request wall.
// ---------------------------------------------------------------------------
__global__ __launch_bounds__(256) void compute_M_kernel(
        const float* __restrict__ Q,
        const float* __restrict__ K,
        const int* __restrict__ idxS,
        float* __restrict__ Mout) {
    int t = blockIdx.x * 256 + threadIdx.x;   // t = b*32768 + l*8 + h
    int h = t & (NH - 1);
    int l = (t >> 3) & (LSEQ - 1);
    int b = t >> 15;

    const float4* qp = reinterpret_cast<const float4*>(
        Q + (((size_t)b * LSEQ + l) * NH + h) * ND);
    float4 q4[16];
    #pragma unroll
    for (int i = 0; i < 16; ++i) q4[i] = qp[i];

    const int* is = idxS + (size_t)l * NSAMP;
    size_t kbh = ((size_t)b * LSEQ * NH + h) * ND;

    float maxv = -INFINITY;
    float sumv = 0.0f;

    for (int s = 0; s < NSAMP; ++s) {
        int idx = is[s];
        const float4* kp = reinterpret_cast<const float4*>(
            K + kbh + (size_t)idx * (NH * ND));
        float4 k4[16];
        #pragma unroll
        for (int i = 0; i < 16; ++i) k4[i] = kp[i];

        // stage off=32 fused with products: w[j] = p[j] + p[j+32]
        float w[32];
        #pragma unroll
        for (int i = 0; i < 8; ++i) {
            float4 a = q4[i], bb = k4[i], c = q4[i + 8], d4 = k4[i + 8];
            w[4 * i + 0] = __fadd_rn(__fmul_rn(a.x, bb.x), __fmul_rn(c.x, d4.x));
            w[4 * i + 1] = __fadd_rn(__fmul_rn(a.y, bb.y), __fmul_rn(c.y, d4.y));
            w[4 * i + 2] = __fadd_rn(__fmul_rn(a.z, bb.z), __fmul_rn(c.z, d4.z));
            w[4 * i + 3] = __fadd_rn(__fmul_rn(a.w, bb.w), __fmul_rn(c.w, d4.w));
        }
        // stages off=16,8,4,2,1
        #pragma unroll
        for (int off = 16; off; off >>= 1) {
            #pragma unroll
            for (int i = 0; i < off; ++i) w[i] = __fadd_rn(w[i], w[i + off]);
        }
        float p = w[0];
        maxv = fmaxf(maxv, p);
        sumv = __fadd_rn(sumv, p);
    }
    Mout[((size_t)b * NH + h) * LSEQ + l] = maxv - sumv * (1.0f / (float)LSEQ);
}

// ---------------------------------------------------------------------------
// Kernel 2: top-45 per (b,h). UNCHANGED (selection semantics frozen).
// ---------------------------------------------------------------------------
__global__ __launch_bounds__(256) void topk_kernel(
        const float* __restrict__ M, int* __restrict__ Mtop) {
    int bh = blockIdx.x;
    int t = threadIdx.x;
    int wave = t >> 6, lane = t & 63;
    const float* m = M + (size_t)bh * LSEQ;

    float rv[16];
    #pragma unroll
    for (int k = 0; k < 16; ++k) rv[k] = m[t + (k << 8)];

    __shared__ float wv[4];
    __shared__ int   wi[4];
    __shared__ int   winIdx;

    for (int iter = 0; iter < NTOP; ++iter) {
        float bv = -INFINITY; int bi = 0x7fffffff;
        #pragma unroll
        for (int k = 0; k < 16; ++k) {
            float v = rv[k];
            if (v > bv) { bv = v; bi = t + (k << 8); }
        }
        #pragma unroll
        for (int off = 1; off < 64; off <<= 1) {
            float ov = __shfl_xor(bv, off, 64);
            int   oi = __shfl_xor(bi, off, 64);
            if (ov > bv || (ov == bv && oi < bi)) { bv = ov; bi = oi; }
        }
        if (lane == 0) { wv[wave] = bv; wi[wave] = bi; }
        __syncthreads();
        if (t == 0) {
            float cv = wv[0]; int ci = wi[0];
            for (int ww = 1; ww < 4; ++ww) {
                if (wv[ww] > cv || (wv[ww] == cv && wi[ww] < ci)) { cv = wv[ww]; ci = wi[ww]; }
            }
            winIdx = ci;
            Mtop[bh * NTOP + iter] = ci;
        }
        __syncthreads();
        int widx = winIdx;
        #pragma unroll
        for (int k = 0; k < 16; ++k)
            if (widx == t + (k << 8)) rv[k] = -INFINITY;
        __syncthreads();
    }
}

// ---------------------------------------------------------------------------
// Kernel 3a: per-chunk sums of V (16 chunks of 256 rows per (b,h)).
// Grid 512 = (bh,c); 256 thr = 4 row-groups x 64 d. Reads 32 MB once.
// ---------------------------------------------------------------------------
__global__ __launch_bounds__(256) void cumsumA_kernel(
        const float* __restrict__ V, float* __restrict__ chunkSums) {
    int blk = blockIdx.x;
    int c = blk & 15;
    int bh = blk >> 4;
    int h = bh & (NH - 1);
    int b = bh >> 3;
    int g = threadIdx.x >> 6, d = threadIdx.x & 63;

    const size_t rstride = (size_t)NH * ND;   // 512
    size_t vbase = (size_t)b * LSEQ * rstride + (size_t)h * ND + d;

    int l0 = c * 256 + g * 64;
    float s = 0.0f;
    for (int l = l0; l < l0 + 64; ++l) s += V[vbase + (size_t)l * rstride];

    __shared__ float part[4][ND];
    part[g][d] = s;
    __syncthreads();
    if (threadIdx.x < ND)
        chunkSums[(size_t)blk * ND + d] =
            part[0][d] + part[1][d] + part[2][d] + part[3][d];
}

// ---------------------------------------------------------------------------
// Kernel 3b: rescan chunk with exclusive prefix from chunkSums, write out.
// Grid 512 = (bh,c); 256 thr = 4 row-groups x 64 d. Reads 32 MB + writes 32.
// ---------------------------------------------------------------------------
__global__ __launch_bounds__(256) void cumsumC_kernel(
        const float* __restrict__ V, const float* __restrict__ chunkSums,
        float* __restrict__ out) {
    int blk = blockIdx.x;
    int c = blk & 15;
    int bh = blk >> 4;
    int h = bh & (NH - 1);
    int b = bh >> 3;
    int g = threadIdx.x >> 6, d = threadIdx.x & 63;

    const size_t rstride = (size_t)NH * ND;
    size_t vbase = (size_t)b * LSEQ * rstride + (size_t)h * ND + d;

    // prefix over earlier chunks
    float run = 0.0f;
    for (int cc = 0; cc < c; ++cc)
        run += chunkSums[((size_t)bh * 16 + cc) * ND + d];

    // within-chunk group partials
    int l0 = c * 256 + g * 64;
    float s = 0.0f;
    for (int l = l0; l < l0 + 64; ++l) s += V[vbase + (size_t)l * rstride];
    __shared__ float part[4][ND];
    part[g][d] = s;
    __syncthreads();
    for (int gg = 0; gg < g; ++gg) run += part[gg][d];

    size_t obase = (size_t)bh * LSEQ * ND + d;
    for (int l = l0; l < l0 + 64; ++l) {
        run += V[vbase + (size_t)l * rstride];
        out[obase + (size_t)l * ND] = run;
    }
}

// ---------------------------------------------------------------------------
// Kernel 4: per (b,h,u) flash attention, LDS-tiled (body as round 6).
// blockIdx remapped so all 45 u-blocks of one (b,h) land on ONE XCD
// (round-robin heuristic) and share the K/V stream in that XCD's L2.
// ---------------------------------------------------------------------------
#define TJ 64
__global__ __launch_bounds__(256) void attn_rows_kernel(
        const float* __restrict__ Q,
        const float* __restrict__ K,
        const float* __restrict__ V,
        const int* __restrict__ Mtop,
        float* __restrict__ out) {
    int x = blockIdx.x;
    int xcd = x & 7;
    int slot = x >> 3;           // 0..179
    int grp = slot / NTOP;       // 0..3
    int u = slot % NTOP;
    int bh = grp * 8 + xcd;      // all u of this bh share an XCD
    int h = bh & (NH - 1);
    int b = bh >> 3;
    int pos = Mtop[bh * NTOP + u];
    int n = pos + 1;
    int t = threadIdx.x;
    int r = t >> 2, qt = t & 3;

    __shared__ float Ks[TJ][65];
    __shared__ float Vs[TJ][65];
    __shared__ float red[256];

    const size_t rstride = (size_t)NH * ND;   // 512
    size_t base = (size_t)b * LSEQ * rstride + (size_t)h * ND;

    float qreg[16];
    const float* qrow = Q + base + (size_t)pos * rstride + qt * 16;
    #pragma unroll
    for (int i = 0; i < 16; i += 4) {
        float4 v4 = *reinterpret_cast<const float4*>(qrow + i);
        qreg[i] = v4.x; qreg[i + 1] = v4.y; qreg[i + 2] = v4.z; qreg[i + 3] = v4.w;
    }

    float m = -INFINITY, s = 0.0f;
    float o[16];
    #pragma unroll
    for (int dd = 0; dd < 16; ++dd) o[dd] = 0.0f;

    int ntiles = (n + TJ - 1) / TJ;
    for (int tt = 0; tt < ntiles; ++tt) {
        int j0 = tt * TJ;
        __syncthreads();
        #pragma unroll
        for (int i = 0; i < 4; ++i) {
            int u16 = t + i * 256;
            int rr = u16 >> 4, cc = u16 & 15;
            int j = j0 + rr;
            int jc = (j < n) ? j : (n - 1);
            const float* rowk = K + base + (size_t)jc * rstride;
            float4 kv = *reinterpret_cast<const float4*>(rowk + cc * 4);
            Ks[rr][cc * 4 + 0] = kv.x; Ks[rr][cc * 4 + 1] = kv.y;
            Ks[rr][cc * 4 + 2] = kv.z; Ks[rr][cc * 4 + 3] = kv.w;
            const float* rowv = V + base + (size_t)jc * rstride;
            float4 vv = *reinterpret_cast<const float4*>(rowv + cc * 4);
            Vs[rr][cc * 4 + 0] = vv.x; Vs[rr][cc * 4 + 1] = vv.y;
            Vs[rr][cc * 4 + 2] = vv.z; Vs[rr][cc * 4 + 3] = vv.w;
        }
        __syncthreads();

        int j = j0 + r;
        float acc = 0.0f;
        #pragma unroll
        for (int dd = 0; dd < 16; ++dd)
            acc = fmaf(qreg[dd], Ks[r][qt * 16 + dd], acc);
        acc += __shfl_xor(acc, 1, 64);
        acc += __shfl_xor(acc, 2, 64);

        if (j < n) {
            float sc = acc * 0.125f;
            if (sc > m) {
                float alpha = __expf(m - sc);
                s *= alpha;
                #pragma unroll
                for (int dd = 0; dd < 16; ++dd) o[dd] *= alpha;
                m = sc;
            }
            float e = __expf(sc - m);
            s += e;
            #pragma unroll
            for (int dd = 0; dd < 16; ++dd)
                o[dd] = fmaf(e, Vs[r][qt * 16 + dd], o[dd]);
        }
    }
    __syncthreads();

    red[t] = m; __syncthreads();
    for (int sft = 128; sft; sft >>= 1) {
        if (t < sft) red[t] = fmaxf(red[t], red[t + sft]);
        __syncthreads();
    }
    float mstar = red[0]; __syncthreads();
    float a = __expf(m - mstar);

    red[t] = s * a; __syncthreads();
    for (int sft = 128; sft; sft >>= 1) {
        if (t < sft) red[t] += red[t + sft];
        __syncthreads();
    }
    float S = red[0]; __syncthreads();

    float* OB = &Ks[0][0];
    #pragma unroll
    for (int dd = 0; dd < 16; ++dd) OB[t * 16 + dd] = o[dd] * a;
    __syncthreads();

    if (t < ND) {
        int qtt = t >> 4, dd = t & 15;
        float tot = 0.0f;
        for (int k = 0; k < 64; ++k) tot += OB[(4 * k + qtt) * 16 + dd];
        out[((size_t)bh * LSEQ + pos) * ND + t] = tot / S;
    }
}

// ---------------------------------------------------------------------------
extern "C" void kernel_launch(void* const* d_in, const int* in_sizes, int n_in,
                              void* d_out, int out_size, void* d_ws, size_t ws_size,
                              hipStream_t stream) {
    const float* Q = (const float*)d_in[0];
    const float* K = (const float*)d_in[1];
    const float* V = (const float*)d_in[2];
    const int* idxS = (const int*)d_in[3];
    float* out = (float*)d_out;

    // M (fp32, 512 KB) lives in d_out — consumed by topk before cumsum
    // overwrites d_out. ws: Mtop (5760 B) @0, chunkSums (128 KB) @8192.
    float* Mbuf = (float*)d_out;
    int*   Mtop = (int*)d_ws;
    float* chunkSums = (float*)((char*)d_ws + 8192);

    compute_M_kernel<<<NB * NH * LSEQ / 256, 256, 0, stream>>>(Q, K, idxS, Mbuf);
    topk_kernel<<<NB * NH, 256, 0, stream>>>(Mbuf, Mtop);
    cumsumA_kernel<<<NB * NH * 16, 256, 0, stream>>>(V, chunkSums);
    cumsumC_kernel<<<NB * NH * 16, 256, 0, stream>>>(V, chunkSums, out);
    attn_rows_kernel<<<NB * NH * NTOP, 256, 0, stream>>>(Q, K, V, Mtop, out);
}